// Round 4
// baseline (328.054 us; speedup 1.0000x reference)
//
#include <hip/hip_runtime.h>

// QuaternionLinear as GEMM: M=32768 (batch), N=1024 (OUT_F*4), K=1024 (IN_F*4).
// W_eff[4o+r][4i+c] = sign(r,c) * weight[o][i][r^c], built in d_ws as bf16.
//
// R4: fuse the fp32->bf16 conversion back into the GEMM — but unlike R2's
// failed fusion (global_load -> vmcnt wait -> cvt -> ds_write exposed ~900cyc
// per iter), A is staged as RAW FP32 via global_load_lds (latency drained at
// the same barrier as B, the proven R3/m97 pattern) and converted during the
// LDS->register fragment read (v_cvt_pk_bf16_f32; VALUBusy had headroom).
// This removes the conv_x pass entirely: total HBM traffic 392 MB -> 263 MB
// (R3 FETCH=66MB proved the xb round-trip was real HBM traffic both ways).
// Keeps: XCD-aware grid swizzle (A fetched from HBM once), XOR bank swizzle
// (verified 0 conflicts in R2/R3), 128x128x64 tiles, 4 waves, 16x16x32 MFMA.

typedef __bf16 bf16x8_t __attribute__((ext_vector_type(8)));
typedef short short8    __attribute__((ext_vector_type(8)));
typedef float f32x4     __attribute__((ext_vector_type(4)));
typedef float f32x8     __attribute__((ext_vector_type(8)));

typedef const unsigned int __attribute__((address_space(1)))* gas_uint_ptr;
typedef unsigned int __attribute__((address_space(3)))*       las_uint_ptr;

// ---------------------------------------------------------------------------
// Prep: build effective bf16 weight matrix W_eff (1024 x 1024), row n = 4o+r,
// col k = 4i+c.  Component select s = r^c; sign bit from table 0x284E.
// ---------------------------------------------------------------------------
__global__ __launch_bounds__(256) void build_weff(const float* __restrict__ w,
                                                  unsigned short* __restrict__ wq) {
    int idx = blockIdx.x * 256 + threadIdx.x;   // 0 .. 1048575
    int n = idx >> 10, k = idx & 1023;
    int o = n >> 2, r = n & 3, i = k >> 2, c = k & 3;
    int s = r ^ c;
    float v = w[o * 1024 + i * 4 + s];
    if ((0x284E >> (r * 4 + c)) & 1) v = -v;
    union { __bf16 b; unsigned short u; } cv;
    cv.b = (__bf16)v;
    wq[idx] = cv.u;
}

// ---------------------------------------------------------------------------
// Fused GEMM. Grid = 2048 blocks.
// XCD swizzle: xcd = bid&7 (HW round-robin), m-tile = xcd*32 + (s>>3), n = s&7.
//
// A tile: 128 rows x 64 fp32 = 32 KiB, stored as 2048 chunks of 16 B (4 f32).
//   Logical (row r, chunk c in 0..15) at position p = r*16 + (c ^ (r&15)).
// B tile: 128 rows x 64 bf16 = 16 KiB, 1024 chunks of 16 B (8 bf16).
//   Logical (row r, chunk g in 0..7)  at position p = r*8  + (g ^ (r&7)).
// global_load_lds destination is lane-contiguous in p (required); the SOURCE
// address is permuted instead.
// ---------------------------------------------------------------------------
__global__ __launch_bounds__(256) void qlin_gemm_f32a(const float* __restrict__ X,
                                                      const unsigned short* __restrict__ Wq,
                                                      const float* __restrict__ bias,
                                                      float* __restrict__ out) {
    __shared__ __align__(16) float          As[128 * 64];   // 32 KiB (fp32!)
    __shared__ __align__(16) unsigned short Bs[128 * 64];   // 16 KiB

    const int t    = threadIdx.x;
    const int w    = t >> 6;
    const int l    = t & 63;
    const int lo16 = l & 15;
    const int hi2  = l >> 4;

    const int bid  = blockIdx.x;
    const int xcd  = bid & 7;
    const int s    = bid >> 3;              // 0..255 within this XCD
    const int m0   = (xcd * 32 + (s >> 3)) * 128;
    const int n0   = (s & 7) * 128;

    const int wm   = (w & 1) * 64;
    const int wn   = (w >> 1) * 64;

    f32x4 acc[4][4] = {};

    for (int kt = 0; kt < 16; ++kt) {
        const int k0 = kt * 64;
        __syncthreads();   // protect LDS being re-filled from prior iter reads

        // --- B tile: 1024 chunks, 4 per thread.
#pragma unroll
        for (int jj = 0; jj < 4; ++jj) {
            const int p   = jj * 256 + t;
            const int row = p >> 3;
            const int g   = (p & 7) ^ (row & 7);
            const unsigned short* gb = Wq + (n0 + row) * 1024 + k0 + g * 8;
            __builtin_amdgcn_global_load_lds((gas_uint_ptr)gb,
                                             (las_uint_ptr)(Bs + p * 8), 16, 0, 0);
        }
        // --- A tile (fp32): 2048 chunks, 8 per thread.
#pragma unroll
        for (int jj = 0; jj < 8; ++jj) {
            const int p   = jj * 256 + t;
            const int row = p >> 4;
            const int c   = (p & 15) ^ (row & 15);
            const float* ga = X + (long long)(m0 + row) * 1024 + k0 + c * 4;
            __builtin_amdgcn_global_load_lds((gas_uint_ptr)ga,
                                             (las_uint_ptr)(As + p * 4), 16, 0, 0);
        }

        __syncthreads();   // drains vmcnt (all global_load_lds)

        // --- Compute: 2 k-steps of 32, 4x4 MFMA tiles per wave.
        // A fragments: read 8 fp32 (2x b128) from swizzled LDS, cvt to bf16x8.
#pragma unroll
        for (int ks = 0; ks < 2; ++ks) {
            const int g = ks * 4 + hi2;     // 8-elem chunk index within row
            short8 af[4], bf[4];
#pragma unroll
            for (int mt = 0; mt < 4; ++mt) {
                const int r  = wm + mt * 16 + lo16;
                const int c0 = (2 * g)     ^ (r & 15);
                const int c1 = (2 * g + 1) ^ (r & 15);
                f32x4 lo = *(const f32x4*)(As + (r * 16 + c0) * 4);
                f32x4 hi = *(const f32x4*)(As + (r * 16 + c1) * 4);
                f32x8 f8 = __builtin_shufflevector(lo, hi, 0, 1, 2, 3, 4, 5, 6, 7);
                bf16x8_t bv = __builtin_convertvector(f8, bf16x8_t);
                union { bf16x8_t b; short8 s; } cv;
                cv.b = bv;
                af[mt] = cv.s;
            }
#pragma unroll
            for (int nt = 0; nt < 4; ++nt) {
                const int r = wn + nt * 16 + lo16;
                bf[nt] = *(const short8*)(Bs + (r * 8 + (g ^ (r & 7))) * 8);
            }
#pragma unroll
            for (int mt = 0; mt < 4; ++mt)
#pragma unroll
                for (int nt = 0; nt < 4; ++nt)
                    acc[mt][nt] = __builtin_amdgcn_mfma_f32_16x16x32_bf16(
                        af[mt], bf[nt], acc[mt][nt], 0, 0, 0);
        }
    }

    // Epilogue: C/D layout col(n) = lane&15, row(m) = (lane>>4)*4 + reg.
#pragma unroll
    for (int nt = 0; nt < 4; ++nt) {
        const int n  = n0 + wn + nt * 16 + lo16;
        const float bv = bias[n];
#pragma unroll
        for (int mt = 0; mt < 4; ++mt) {
            const int mb = m0 + wm + mt * 16 + hi2 * 4;
#pragma unroll
            for (int r = 0; r < 4; ++r)
                out[(long long)(mb + r) * 1024 + n] = acc[mt][nt][r] + bv;
        }
    }
}

// ---------------------------------------------------------------------------
extern "C" void kernel_launch(void* const* d_in, const int* in_sizes, int n_in,
                              void* d_out, int out_size, void* d_ws, size_t ws_size,
                              hipStream_t stream) {
    const float* x  = (const float*)d_in[0];   // (32768, 256, 4) fp32
    const float* wt = (const float*)d_in[1];   // (256, 256, 4) fp32
    const float* bs = (const float*)d_in[2];   // (256, 4) fp32
    float* out = (float*)d_out;                // (32768, 256, 4) fp32
    unsigned short* wq = (unsigned short*)d_ws; // 2 MiB W_eff bf16

    build_weff<<<4096, 256, 0, stream>>>(wt, wq);
    qlin_gemm_f32a<<<2048, 256, 0, stream>>>(x, wq, bs, out);

    (void)in_sizes; (void)n_in; (void)out_size; (void)ws_size;
}